// Round 13
// baseline (200.349 us; speedup 1.0000x reference)
//
#include <hip/hip_runtime.h>
#include <math.h>

// completeNet: graph-net + Sinkhorn, 5 dispatches (R10/R12 structure).
// T=256 tracks (nodes 0..255), M=256 dets (nodes 256..511), D_IN=512, D_EMB=256.
//   k1: hAB[2][512][256] = x@Wc K-halves (raw), grid (8,16,2) = 256 blocks.
//   k2: 192 blocks x 512 thr (single scheduling generation; two 32-col tiles
//       share one Ast stage). relu(hA+hB+bc) in-load -> PT / PQGW cols 128..767.
//   k34: 256 blocks x 2 rows (same side), E-rows in LDS, out rows + norms.
//   k6: 64-block GEMM Out_track@Out_det^T + inline iou + score MLP -> Mh (fp16
//       half2 — k7 consumes fp16 anyway; conversion moved here, bit-identical).
//   k7: Sinkhorn, 1 block, M register-resident fp16 (loads Mh directly).

__device__ __forceinline__ float sigmoidf_(float x) { return 1.0f / (1.0f + expf(-x)); }

typedef _Float16 h2t __attribute__((ext_vector_type(2)));

__device__ __forceinline__ h2t pack2(float x, float y) {
  h2t r; r.x = (_Float16)x; r.y = (_Float16)y; return r;
}
__device__ __forceinline__ float fdot2f(h2t a, h2t b, float c) {
  return __builtin_amdgcn_fdot2(a, b, c, false);
}
template <int CTRL>
__device__ __forceinline__ float dpp_get(float x) {
  return __builtin_bit_cast(
      float, __builtin_amdgcn_mov_dpp(__builtin_bit_cast(int, x), CTRL, 0xF, 0xF, false));
}
template <int IMM>
__device__ __forceinline__ float swz_get(float x) {
  return __builtin_bit_cast(
      float, __builtin_amdgcn_ds_swizzle(__builtin_bit_cast(int, x), IMM));
}
__device__ __forceinline__ float allred16(float x) {
  x += dpp_get<0xB1>(x);   // xor1
  x += dpp_get<0x4E>(x);   // xor2
  x += dpp_get<0x141>(x);  // xor7
  x += dpp_get<0x140>(x);  // xor15
  return x;
}

#define G_LOAD(T, AREG, BARR, AP, BP, LDB)                             \
  {                                                                    \
    AREG = *reinterpret_cast<const float4*>((AP) + (T) * 32);          \
    _Pragma("unroll") for (int kk = 0; kk < 32; ++kk)                  \
        BARR[kk] = (BP)[((T) * 32 + kk) * (LDB)];                      \
  }
#define G_STORE(BUF, AREG)                                             \
  {                                                                    \
    Ast[BUF][ac + 0][ar] = AREG.x; Ast[BUF][ac + 1][ar] = AREG.y;      \
    Ast[BUF][ac + 2][ar] = AREG.z; Ast[BUF][ac + 3][ar] = AREG.w;      \
  }
#define G_COMP(BUF, BARR)                                              \
  {                                                                    \
    _Pragma("unroll") for (int kk = 0; kk < 32; ++kk) {                \
      const float4 a4 =                                                \
          *reinterpret_cast<const float4*>(&Ast[BUF][kk][4 * ty]);     \
      const float bv = BARR[kk];                                       \
      acc[0] = fmaf(a4.x, bv, acc[0]); acc[1] = fmaf(a4.y, bv, acc[1]);\
      acc[2] = fmaf(a4.z, bv, acc[2]); acc[3] = fmaf(a4.w, bv, acc[3]);\
    }                                                                  \
  }

// ---------------------------------------------------------------------------
// K1: hAB[z] = x[:, z*256:(z+1)*256] @ Wc[z*256:(z+1)*256, :]  (raw partials)
__global__ __launch_bounds__(256)
void k1_h(const float* __restrict__ x, const float* __restrict__ Wc,
          float* __restrict__ hAB) {
  __shared__ __align__(16) float Ast[2][32][36];
  const int tid = threadIdx.x;
  const int tx = tid & 31, ty = tid >> 5;
  const int ar = tid >> 3, ac = (tid & 7) * 4;
  const int bm = blockIdx.y * 32, bn = blockIdx.x * 32;
  const int z = blockIdx.z;
  const float* __restrict__ Bp = Wc + (z * 256) * 256 + bn + tx;
  const float* __restrict__ Ap = x + (bm + ar) * 512 + z * 256 + ac;
  float* __restrict__ Cout = hAB + z * 131072;
  float4 aA, aB;
  float bA[32], bB[32];
  float acc[4] = {0.f, 0.f, 0.f, 0.f};

  G_LOAD(0, aA, bA, Ap, Bp, 256);
  G_STORE(0, aA);
  __syncthreads();
  for (int t = 0; t < 8; t += 2) {
    G_LOAD(t + 1, aB, bB, Ap, Bp, 256);
    G_COMP(0, bA);
    G_STORE(1, aB);
    __syncthreads();
    if (t + 2 < 8) { G_LOAD(t + 2, aA, bA, Ap, Bp, 256); }
    G_COMP(1, bB);
    if (t + 2 < 8) { G_STORE(0, aA); }
    __syncthreads();
  }
#pragma unroll
  for (int i = 0; i < 4; ++i)
    Cout[(bm + 4 * ty + i) * 256 + bn + tx] = acc[i];
}

// ---------------------------------------------------------------------------
// K2: 512 threads, 64 output cols per block (two 32-col halves share Ast).
// A = relu(hA+hB+bc) in-load (threads <256 stage). grid (12,16) = 192 blocks.
__global__ __launch_bounds__(512)
void k2_pqgw(const float* __restrict__ hAB, const float* __restrict__ bc,
             const float* __restrict__ W1, const float* __restrict__ b1,
             const float* __restrict__ Wo2, const float* __restrict__ Wo1,
             float* __restrict__ PQGW, float* __restrict__ PT) {
  __shared__ __align__(16) float Ast[2][32][36];
  const int tid = threadIdx.x;
  const int t8 = tid & 255;
  const int tx = t8 & 31, ty = t8 >> 5;
  const int ar = tid >> 3, ac = (tid & 7) * 4;  // staging ids (tid<256 only)
  const int bm = blockIdx.y * 32;
  const int bn = blockIdx.x * 64 + (tid >> 8) * 32;  // per-half column base
  const int col = bn + tx;
  const float* __restrict__ Bp;
  int ldb;
  if (bn < 128)       { Bp = W1 + col; ldb = 128; }
  else if (bn < 256)  { Bp = W1 + 256 * 128 + (col - 128); ldb = 128; }
  else if (bn < 512)  { Bp = Wo2 + (col - 256); ldb = 256; }
  else                { Bp = Wo1 + (col - 512); ldb = 256; }
  const float* __restrict__ ApA = hAB + (bm + ar) * 256 + ac;
  const float* __restrict__ ApB = ApA + 131072;
  const float* __restrict__ bcp = bc + ac;
  float4 aA, aB;
  float bA[32], bB[32];
  float acc[4] = {0.f, 0.f, 0.f, 0.f};

#define K2_LOAD(T, AREG, BARR)                                         \
  {                                                                    \
    if (tid < 256) {                                                   \
      const float4 xa = *reinterpret_cast<const float4*>(ApA + (T) * 32);\
      const float4 xb = *reinterpret_cast<const float4*>(ApB + (T) * 32);\
      const float4 xc = *reinterpret_cast<const float4*>(bcp + (T) * 32);\
      AREG.x = fmaxf(xa.x + xb.x + xc.x, 0.f);                         \
      AREG.y = fmaxf(xa.y + xb.y + xc.y, 0.f);                         \
      AREG.z = fmaxf(xa.z + xb.z + xc.z, 0.f);                         \
      AREG.w = fmaxf(xa.w + xb.w + xc.w, 0.f);                         \
    }                                                                  \
    _Pragma("unroll") for (int kk = 0; kk < 32; ++kk)                  \
        BARR[kk] = Bp[((T) * 32 + kk) * ldb];                          \
  }
#define K2_STORE(BUF, AREG)                                            \
  {                                                                    \
    if (tid < 256) {                                                   \
      Ast[BUF][ac + 0][ar] = AREG.x; Ast[BUF][ac + 1][ar] = AREG.y;    \
      Ast[BUF][ac + 2][ar] = AREG.z; Ast[BUF][ac + 3][ar] = AREG.w;    \
    }                                                                  \
  }

  K2_LOAD(0, aA, bA);
  K2_STORE(0, aA);
  __syncthreads();
  for (int t = 0; t < 8; t += 2) {
    K2_LOAD(t + 1, aB, bB);
    G_COMP(0, bA);
    K2_STORE(1, aB);
    __syncthreads();
    if (t + 2 < 8) { K2_LOAD(t + 2, aA, bA); }
    G_COMP(1, bB);
    if (t + 2 < 8) { K2_STORE(0, aA); }
    __syncthreads();
  }
  if (bn < 128) {
    const float bias = b1[col];
#pragma unroll
    for (int i = 0; i < 4; ++i)
      PT[col * 512 + bm + 4 * ty + i] = acc[i] + bias;
  } else {
#pragma unroll
    for (int i = 0; i < 4; ++i)
      PQGW[(bm + 4 * ty + i) * 768 + col] = acc[i];
  }
#undef K2_LOAD
#undef K2_STORE
}

// ---------------------------------------------------------------------------
// K34: 256 blocks; block q owns rows r0=2q, r1=2q+1 (same side). Shared
// PT/G streams, shared geo inner dot; E-rows in LDS; out rows + norms.
__global__ __launch_bounds__(256)
void k34_edges_out(const float* __restrict__ PQGW, const float* __restrict__ PT,
                   const float* __restrict__ coords, const float* __restrict__ Wapp2,
                   const float* __restrict__ bapp2, const float* __restrict__ Wg1,
                   const float* __restrict__ bg1, const float* __restrict__ Wg2,
                   const float* __restrict__ bg2, const float* __restrict__ Wa1,
                   const float* __restrict__ ba1, const float* __restrict__ Wa2,
                   const float* __restrict__ ba2, const float* __restrict__ bo,
                   float* __restrict__ outm, float* __restrict__ nrm) {
  __shared__ __align__(16) float4 qqw[128];   // {Q[r0][j], Q[r1][j], W2[j], -}
  __shared__ __align__(16) float sWg1[256], sWg2[32], sGfix0[32], sGfix1[32];
  __shared__ __align__(16) float sE0[256], sE1[256];
  __shared__ float sWa1[16], sBa1[8], sWa2[8], wpart[2][4];
  const int tid = threadIdx.x;
  const int q = blockIdx.x;
  const int r0 = 2 * q, r1 = 2 * q + 1;
  const bool istrack = (r0 < 256);
  const int vbase = istrack ? 256 : 0;

  if (tid < 128) {
    float4 t;
    t.x = PQGW[r0 * 768 + 128 + tid];
    t.y = PQGW[r1 * 768 + 128 + tid];
    t.z = Wapp2[tid];
    t.w = 0.f;
    qqw[tid] = t;
  }
  sWg1[tid] = Wg1[tid];
  if (tid < 32) sWg2[tid] = Wg2[tid];
  if (tid < 16) sWa1[tid] = Wa1[tid];
  if (tid < 8) { sBa1[tid] = ba1[tid]; sWa2[tid] = Wa2[tid]; }
  __syncthreads();
  if (tid < 32) {  // fixed nodes in DST slot: Wg1 rows 4..7
    float g0 = bg1[tid], g1 = g0;
#pragma unroll
    for (int p = 0; p < 4; ++p) {
      g0 = fmaf(coords[r0 * 4 + p], sWg1[(4 + p) * 32 + tid], g0);
      g1 = fmaf(coords[r1 * 4 + p], sWg1[(4 + p) * 32 + tid], g1);
    }
    sGfix0[tid] = g0;
    sGfix1[tid] = g1;
  }
  __syncthreads();

  const int vr = vbase + tid;
  const float* __restrict__ ptb = PT + vr;
  float z0 = 0.f, z1 = 0.f;
#pragma unroll 8
  for (int j = 0; j < 128; ++j) {
    const float4 t = qqw[j];
    const float p = ptb[j * 512];
    float a0 = p + t.x; a0 = a0 > 0.f ? a0 : 0.f; z0 = fmaf(a0, t.z, z0);
    float a1 = p + t.y; a1 = a1 > 0.f ? a1 : 0.f; z1 = fmaf(a1, t.z, z1);
  }
  const float app0 = sigmoidf_(z0 + bapp2[0]);
  const float app1 = sigmoidf_(z1 + bapp2[0]);
  const float4 cp = *reinterpret_cast<const float4*>(coords + vr * 4);
  float gz0 = 0.f, gz1 = 0.f;
#pragma unroll
  for (int m = 0; m < 32; ++m) {
    float dm = cp.x * sWg1[m];
    dm = fmaf(cp.y, sWg1[32 + m], dm);
    dm = fmaf(cp.z, sWg1[64 + m], dm);
    dm = fmaf(cp.w, sWg1[96 + m], dm);
    float h0 = sGfix0[m] + dm;
    h0 = h0 > 0.f ? h0 : 0.f;
    gz0 = fmaf(h0, sWg2[m], gz0);
    float h1 = sGfix1[m] + dm;
    h1 = h1 > 0.f ? h1 : 0.f;
    gz1 = fmaf(h1, sWg2[m], gz1);
  }
  const float geo0 = sigmoidf_(gz0 + bg2[0]);
  const float geo1 = sigmoidf_(gz1 + bg2[0]);
  float ez0 = 0.f, ez1 = 0.f;
#pragma unroll
  for (int m = 0; m < 8; ++m) {
    float h0 = fmaf(app0, sWa1[m], fmaf(geo0, sWa1[8 + m], sBa1[m]));
    h0 = h0 > 0.f ? h0 : 0.f;
    ez0 = fmaf(h0, sWa2[m], ez0);
    float h1 = fmaf(app1, sWa1[m], fmaf(geo1, sWa1[8 + m], sBa1[m]));
    h1 = h1 > 0.f ? h1 : 0.f;
    ez1 = fmaf(h1, sWa2[m], ez1);
  }
  sE0[tid] = sigmoidf_(ez0 + ba2[0]);
  sE1[tid] = sigmoidf_(ez1 + ba2[0]);
  __syncthreads();

  const int c = tid;
  float acc0[4] = {0.f, 0.f, 0.f, 0.f}, acc1[4] = {0.f, 0.f, 0.f, 0.f};
  const float* __restrict__ gcol = PQGW + vbase * 768 + 256 + c;
#pragma unroll 2
  for (int j = 0; j < 256; j += 8) {
    const float4 e0a = *reinterpret_cast<const float4*>(&sE0[j]);
    const float4 e0b = *reinterpret_cast<const float4*>(&sE0[j + 4]);
    const float4 e1a = *reinterpret_cast<const float4*>(&sE1[j]);
    const float4 e1b = *reinterpret_cast<const float4*>(&sE1[j + 4]);
    const float g0 = gcol[(j + 0) * 768];
    const float g1 = gcol[(j + 1) * 768];
    const float g2 = gcol[(j + 2) * 768];
    const float g3 = gcol[(j + 3) * 768];
    const float g4 = gcol[(j + 4) * 768];
    const float g5 = gcol[(j + 5) * 768];
    const float g6 = gcol[(j + 6) * 768];
    const float g7 = gcol[(j + 7) * 768];
    acc0[0] = fmaf(e0a.x, g0, acc0[0]); acc1[0] = fmaf(e1a.x, g0, acc1[0]);
    acc0[1] = fmaf(e0a.y, g1, acc0[1]); acc1[1] = fmaf(e1a.y, g1, acc1[1]);
    acc0[2] = fmaf(e0a.z, g2, acc0[2]); acc1[2] = fmaf(e1a.z, g2, acc1[2]);
    acc0[3] = fmaf(e0a.w, g3, acc0[3]); acc1[3] = fmaf(e1a.w, g3, acc1[3]);
    acc0[0] = fmaf(e0b.x, g4, acc0[0]); acc1[0] = fmaf(e1b.x, g4, acc1[0]);
    acc0[1] = fmaf(e0b.y, g5, acc0[1]); acc1[1] = fmaf(e1b.y, g5, acc1[1]);
    acc0[2] = fmaf(e0b.z, g6, acc0[2]); acc1[2] = fmaf(e1b.z, g6, acc1[2]);
    acc0[3] = fmaf(e0b.w, g7, acc0[3]); acc1[3] = fmaf(e1b.w, g7, acc1[3]);
  }
  const float boc = bo[c];
  float vv0 = PQGW[r0 * 768 + 512 + c] + boc +
              ((acc0[0] + acc0[1]) + (acc0[2] + acc0[3]));
  float vv1 = PQGW[r1 * 768 + 512 + c] + boc +
              ((acc1[0] + acc1[1]) + (acc1[2] + acc1[3]));
  vv0 = vv0 > 0.f ? vv0 : 0.f;
  vv1 = vv1 > 0.f ? vv1 : 0.f;
  outm[r0 * 256 + c] = vv0;
  outm[r1 * 256 + c] = vv1;
  float ns0 = vv0 * vv0, ns1 = vv1 * vv1;
  ns0 = allred16(ns0);
  ns0 += swz_get<0x401F>(ns0);
  ns0 += __shfl_xor(ns0, 32, 64);
  ns1 = allred16(ns1);
  ns1 += swz_get<0x401F>(ns1);
  ns1 += __shfl_xor(ns1, 32, 64);
  if ((tid & 63) == 0) {
    wpart[0][tid >> 6] = ns0;
    wpart[1][tid >> 6] = ns1;
  }
  __syncthreads();
  if (tid == 0)
    nrm[r0] = fmaxf(sqrtf(wpart[0][0] + wpart[0][1] + wpart[0][2] + wpart[0][3]),
                    1e-6f);
  if (tid == 1)
    nrm[r1] = fmaxf(sqrtf(wpart[1][0] + wpart[1][1] + wpart[1][2] + wpart[1][3]),
                    1e-6f);
}

// ---------------------------------------------------------------------------
// K6: Mh = fp16(exp(5*score(cos, iou))) as half2 (k7 consumes fp16; RNE here
// is bit-identical to k7's former pack2). grid (8,8).
__global__ __launch_bounds__(256)
void k6_score(const float* __restrict__ outm, const float* __restrict__ nrm,
              const float* __restrict__ co, const float* __restrict__ Wf1,
              const float* __restrict__ bf1, const float* __restrict__ Wf2,
              const float* __restrict__ bf2, h2t* __restrict__ Mh) {
  __shared__ __align__(16) float Ast[2][32][36];
  const int tid = threadIdx.x;
  const int tx = tid & 31, ty = tid >> 5;
  const int ar = tid >> 3, ac = (tid & 7) * 4;
  const int s0 = blockIdx.y * 32, d0 = blockIdx.x * 32;
  const float* __restrict__ Ap = outm + (s0 + ar) * 256 + ac;
  const float* __restrict__ Bp = outm + (256 + d0 + tx) * 256;  // det row, ldb=1
  float4 aA, aB;
  float bA[32], bB[32];
  float acc[4] = {0.f, 0.f, 0.f, 0.f};

  G_LOAD(0, aA, bA, Ap, Bp, 1);
  G_STORE(0, aA);
  __syncthreads();
  for (int t = 0; t < 8; t += 2) {
    G_LOAD(t + 1, aB, bB, Ap, Bp, 1);
    G_COMP(0, bA);
    G_STORE(1, aB);
    __syncthreads();
    if (t + 2 < 8) { G_LOAD(t + 2, aA, bA, Ap, Bp, 1); }
    G_COMP(1, bB);
    if (t + 2 < 8) { G_STORE(0, aA); }
    __syncthreads();
  }
  const float nb = nrm[256 + d0 + tx];
  const float4 B4 = *reinterpret_cast<const float4*>(co + (256 + d0 + tx) * 4);
  const float areaB = (B4.z - B4.x) * (B4.w - B4.y);
  float w1c[8], w1i[8], w2[8];
#pragma unroll
  for (int m = 0; m < 8; ++m) {
    w1c[m] = Wf1[m]; w1i[m] = Wf1[8 + m]; w2[m] = Wf2[m];
  }
  const float bf20 = bf2[0];
#pragma unroll
  for (int i = 0; i < 4; ++i) {
    const int r = s0 + 4 * ty + i;
    const float4 A4 = *reinterpret_cast<const float4*>(co + r * 4);
    const float ix1 = fmaxf(A4.x, B4.x), iy1 = fmaxf(A4.y, B4.y);
    const float ix2 = fminf(A4.z, B4.z), iy2 = fminf(A4.w, B4.w);
    const float inter = fmaxf(ix2 - ix1, 0.f) * fmaxf(iy2 - iy1, 0.f);
    const float areaA = (A4.z - A4.x) * (A4.w - A4.y);
    const float i1 = inter / (areaA + areaB - inter + 1e-8f);
    const float cosv = acc[i] / (nrm[r] * nb);
    float sz = 0.f;
#pragma unroll
    for (int m = 0; m < 8; ++m) {
      float hm = fmaf(cosv, w1c[m], fmaf(i1, w1i[m], bf1[m]));
      hm = hm > 0.f ? hm : 0.f;
      sz = fmaf(hm, w2[m], sz);
    }
    const float score = sigmoidf_(sz + bf20);
    const float mv = expf(5.0f * score);
    const float nbr = __shfl_xor(mv, 1, 64);  // pair (tx even, tx odd)
    if ((tx & 1) == 0)
      Mh[r * 128 + ((d0 + tx) >> 1)] = pack2(mv, nbr);
  }
}

// ---------------------------------------------------------------------------
// K7: Sinkhorn, single 1024-thread block, M register-resident (fp16, loaded
// directly from Mh — half the read traffic, no cvt in staging).
__global__ __launch_bounds__(1024)
void k7_sink(const h2t* __restrict__ Mh, float* __restrict__ outp) {
  __shared__ __align__(16) float su_f[256];
  __shared__ __align__(16) float svs_f[256];   // 256*sv
  __shared__ __align__(16) float psum[16][260];
  __shared__ float wsumU[16], wsumV[4];
  const int tid = threadIdx.x, w = tid >> 6, l = tid & 63;
  const float slack = 2.71828182845904523536f;  // exp(LAM*SLACK) = exp(1)
  const float INV256 = 0.00390625f;
  const int rev = ((l & 1) << 3) | ((l & 2) << 1) | ((l & 4) >> 1) | ((l & 8) >> 3);
  const bool b0 = l & 1, b1 = l & 2, b2 = l & 4, b3 = l & 8;

  h2t mrA[16], mrB[16];
#pragma unroll
  for (int i = 0; i < 16; ++i) {
    const uint2 u = *reinterpret_cast<const uint2*>(Mh + (w * 16 + i) * 128 + 2 * l);
    mrA[i] = __builtin_bit_cast(h2t, u.x);
    mrB[i] = __builtin_bit_cast(h2t, u.y);
  }
  if (tid < 256) svs_f[tid] = 256.0f;
  __syncthreads();

  float sv256 = 1.0f;
  for (int it = 0; it < 8; ++it) {
    const float sv_tot =
        (it == 0) ? 257.0f : (wsumV[0] + wsumV[1] + wsumV[2] + wsumV[3] + sv256);
    const float su256 = 1.0f / (slack * sv_tot);
    // row pass
    const float4 va = *reinterpret_cast<const float4*>(&svs_f[4 * l]);
    const h2t sva = pack2(va.x, va.y), svb = pack2(va.z, va.w);
    float p[16];
#pragma unroll
    for (int i = 0; i < 16; ++i) p[i] = fdot2f(mrA[i], sva, fdot2f(mrB[i], svb, 0.0f));
#pragma unroll
    for (int i = 0; i < 8; ++i) {
      const float keep = b0 ? p[i + 8] : p[i], give = b0 ? p[i] : p[i + 8];
      p[i] = keep + dpp_get<0xB1>(give);
    }
#pragma unroll
    for (int i = 0; i < 4; ++i) {
      const float keep = b1 ? p[i + 4] : p[i], give = b1 ? p[i] : p[i + 4];
      p[i] = keep + dpp_get<0x4E>(give);
    }
#pragma unroll
    for (int i = 0; i < 2; ++i) {
      const float keep = b2 ? p[i + 2] : p[i], give = b2 ? p[i] : p[i + 2];
      p[i] = keep + dpp_get<0x141>(give);
    }
    {
      const float keep = b3 ? p[1] : p[0], give = b3 ? p[0] : p[1];
      p[0] = keep + dpp_get<0x140>(give);
    }
    float S = p[0];
    S += swz_get<0x401F>(S);
    S += __shfl_xor(S, 32, 64);
    const float su_val = 1.0f / (S * INV256 + slack * sv256);
    if (l < 16) su_f[w * 16 + rev] = su_val;
    const float wsU = allred16(su_val);
    if (l == 0) wsumU[w] = wsU;
    asm volatile("s_waitcnt lgkmcnt(0)" ::: "memory");  // same-wave su_f readback
    // col partials from row regs
    float su16[16];
#pragma unroll
    for (int k = 0; k < 16; k += 4) {
      const float4 t = *reinterpret_cast<const float4*>(&su_f[w * 16 + k]);
      su16[k] = t.x; su16[k + 1] = t.y; su16[k + 2] = t.z; su16[k + 3] = t.w;
    }
    float pc0 = 0.f, pc1 = 0.f, pc2 = 0.f, pc3 = 0.f;
#pragma unroll
    for (int i = 0; i < 16; ++i) {
      const float ui = su16[i];
      pc0 = fmaf((float)mrA[i].x, ui, pc0);
      pc1 = fmaf((float)mrA[i].y, ui, pc1);
      pc2 = fmaf((float)mrB[i].x, ui, pc2);
      pc3 = fmaf((float)mrB[i].y, ui, pc3);
    }
    float4 pcv; pcv.x = pc0; pcv.y = pc1; pcv.z = pc2; pcv.w = pc3;
    *reinterpret_cast<float4*>(&psum[w][4 * l]) = pcv;
    __syncthreads();
    // sv phase
    const float su_tot = wsumU[0] + wsumU[1] + wsumU[2] + wsumU[3] + wsumU[4] +
                         wsumU[5] + wsumU[6] + wsumU[7] + wsumU[8] + wsumU[9] +
                         wsumU[10] + wsumU[11] + wsumU[12] + wsumU[13] +
                         wsumU[14] + wsumU[15] + su256;
    if (tid < 256) {
      float cs = 0.f;
#pragma unroll
      for (int g = 0; g < 16; ++g) cs += psum[g][tid];
      const float sv_val = 1.0f / (cs + slack * su256);
      svs_f[tid] = 256.0f * sv_val;
      float t = allred16(sv_val);
      t += swz_get<0x401F>(t);
      t += __shfl_xor(t, 32, 64);
      if (l == 0) wsumV[w] = t;
    }
    sv256 = 1.0f / (slack * su_tot);
    __syncthreads();
  }
  const float4 sv4 = *reinterpret_cast<const float4*>(&svs_f[4 * l]);
#pragma unroll
  for (int i = 0; i < 16; ++i) {
    const float uo = su_f[w * 16 + i] * INV256;
    float4 o;
    o.x = uo * (float)mrA[i].x * sv4.x;
    o.y = uo * (float)mrA[i].y * sv4.y;
    o.z = uo * (float)mrB[i].x * sv4.z;
    o.w = uo * (float)mrB[i].y * sv4.w;
    *reinterpret_cast<float4*>(outp + (w * 16 + i) * 256 + 4 * l) = o;
  }
}

// ---------------------------------------------------------------------------
extern "C" void kernel_launch(void* const* d_in, const int* in_sizes, int n_in,
                              void* d_out, int out_size, void* d_ws, size_t ws_size,
                              hipStream_t stream) {
  (void)in_sizes; (void)n_in; (void)out_size; (void)ws_size;
  const float* x      = (const float*)d_in[0];
  const float* coords = (const float*)d_in[1];
  const float* co     = (const float*)d_in[2];
  // d_in[3] = edge_index (int32) — structure is deterministic, not needed
  const float* Wc    = (const float*)d_in[4];
  const float* bc    = (const float*)d_in[5];
  const float* Wapp1 = (const float*)d_in[6];
  const float* bapp1 = (const float*)d_in[7];
  const float* Wapp2 = (const float*)d_in[8];
  const float* bapp2 = (const float*)d_in[9];
  const float* Wg1   = (const float*)d_in[10];
  const float* bg1   = (const float*)d_in[11];
  const float* Wg2   = (const float*)d_in[12];
  const float* bg2   = (const float*)d_in[13];
  const float* Wa1   = (const float*)d_in[14];
  const float* ba1   = (const float*)d_in[15];
  const float* Wa2   = (const float*)d_in[16];
  const float* ba2   = (const float*)d_in[17];
  const float* Wo1   = (const float*)d_in[18];
  const float* Wo2   = (const float*)d_in[19];
  const float* bo    = (const float*)d_in[20];
  const float* Wf1   = (const float*)d_in[21];
  const float* bf1   = (const float*)d_in[22];
  const float* Wf2   = (const float*)d_in[23];
  const float* bf2   = (const float*)d_in[24];

  float* ws   = (float*)d_ws;
  float* hAB  = ws + 0;        // 2 * 512*256
  float* PQGW = ws + 262144;   // 512*768 (cols 0..127 unused)
  float* PT   = ws + 655360;   // 128*512 (P transposed, +bapp1)
  float* outm = ws + 720896;   // 512*256
  float* nrm  = ws + 851968;   // 512
  h2t*   Mh   = (h2t*)(ws + 852480);  // 256*128 half2 (fp16 M)

  k1_h<<<dim3(8, 16, 2), 256, 0, stream>>>(x, Wc, hAB);
  k2_pqgw<<<dim3(12, 16), 512, 0, stream>>>(hAB, bc, Wapp1, bapp1, Wo2, Wo1,
                                            PQGW, PT);
  k34_edges_out<<<256, 256, 0, stream>>>(PQGW, PT, coords, Wapp2, bapp2, Wg1,
                                         bg1, Wg2, bg2, Wa1, ba1, Wa2, ba2, bo,
                                         outm, nrm);
  k6_score<<<dim3(8, 8), 256, 0, stream>>>(outm, nrm, co, Wf1, bf1, Wf2, bf2,
                                           Mh);
  k7_sink<<<1, 1024, 0, stream>>>(Mh, (float*)d_out);
}

// Round 14
// 88.833 us; speedup vs baseline: 2.2553x; 2.2553x over previous
//
#include <hip/hip_runtime.h>
#include <math.h>

// completeNet: graph-net + Sinkhorn, 5 dispatches (R12 structure + fp16 Mh
// handoff; k2@512-thread variant reverted — R13 lesson: 256-thr column-
// stationary GEMM shape is tuned, widening blocks broke its B-stream).
//   k1: hAB[2][512][256] = x@Wc K-halves (raw), grid (8,16,2).
//   k2: 256 thr, grid (24,16). relu(hA+hB+bc) in-load -> PT / PQGW 128..767.
//   k34: 256 blocks x 2 rows (same side), E-rows in LDS, out rows + norms.
//   k6: 64-block GEMM Out_track@Out_det^T + inline iou + score MLP -> Mh fp16.
//   k7: Sinkhorn, 1 block, M register-resident fp16 (loads Mh directly).

__device__ __forceinline__ float sigmoidf_(float x) { return 1.0f / (1.0f + expf(-x)); }

typedef _Float16 h2t __attribute__((ext_vector_type(2)));

__device__ __forceinline__ h2t pack2(float x, float y) {
  h2t r; r.x = (_Float16)x; r.y = (_Float16)y; return r;
}
__device__ __forceinline__ float fdot2f(h2t a, h2t b, float c) {
  return __builtin_amdgcn_fdot2(a, b, c, false);
}
template <int CTRL>
__device__ __forceinline__ float dpp_get(float x) {
  return __builtin_bit_cast(
      float, __builtin_amdgcn_mov_dpp(__builtin_bit_cast(int, x), CTRL, 0xF, 0xF, false));
}
template <int IMM>
__device__ __forceinline__ float swz_get(float x) {
  return __builtin_bit_cast(
      float, __builtin_amdgcn_ds_swizzle(__builtin_bit_cast(int, x), IMM));
}
__device__ __forceinline__ float allred16(float x) {
  x += dpp_get<0xB1>(x);   // xor1
  x += dpp_get<0x4E>(x);   // xor2
  x += dpp_get<0x141>(x);  // xor7
  x += dpp_get<0x140>(x);  // xor15
  return x;
}

#define G_LOAD(T, AREG, BARR, AP, BP, LDB)                             \
  {                                                                    \
    AREG = *reinterpret_cast<const float4*>((AP) + (T) * 32);          \
    _Pragma("unroll") for (int kk = 0; kk < 32; ++kk)                  \
        BARR[kk] = (BP)[((T) * 32 + kk) * (LDB)];                      \
  }
#define G_STORE(BUF, AREG)                                             \
  {                                                                    \
    Ast[BUF][ac + 0][ar] = AREG.x; Ast[BUF][ac + 1][ar] = AREG.y;      \
    Ast[BUF][ac + 2][ar] = AREG.z; Ast[BUF][ac + 3][ar] = AREG.w;      \
  }
#define G_COMP(BUF, BARR)                                              \
  {                                                                    \
    _Pragma("unroll") for (int kk = 0; kk < 32; ++kk) {                \
      const float4 a4 =                                                \
          *reinterpret_cast<const float4*>(&Ast[BUF][kk][4 * ty]);     \
      const float bv = BARR[kk];                                       \
      acc[0] = fmaf(a4.x, bv, acc[0]); acc[1] = fmaf(a4.y, bv, acc[1]);\
      acc[2] = fmaf(a4.z, bv, acc[2]); acc[3] = fmaf(a4.w, bv, acc[3]);\
    }                                                                  \
  }

// ---------------------------------------------------------------------------
// K1: hAB[z] = x[:, z*256:(z+1)*256] @ Wc[z*256:(z+1)*256, :]  (raw partials)
__global__ __launch_bounds__(256)
void k1_h(const float* __restrict__ x, const float* __restrict__ Wc,
          float* __restrict__ hAB) {
  __shared__ __align__(16) float Ast[2][32][36];
  const int tid = threadIdx.x;
  const int tx = tid & 31, ty = tid >> 5;
  const int ar = tid >> 3, ac = (tid & 7) * 4;
  const int bm = blockIdx.y * 32, bn = blockIdx.x * 32;
  const int z = blockIdx.z;
  const float* __restrict__ Bp = Wc + (z * 256) * 256 + bn + tx;
  const float* __restrict__ Ap = x + (bm + ar) * 512 + z * 256 + ac;
  float* __restrict__ Cout = hAB + z * 131072;
  float4 aA, aB;
  float bA[32], bB[32];
  float acc[4] = {0.f, 0.f, 0.f, 0.f};

  G_LOAD(0, aA, bA, Ap, Bp, 256);
  G_STORE(0, aA);
  __syncthreads();
  for (int t = 0; t < 8; t += 2) {
    G_LOAD(t + 1, aB, bB, Ap, Bp, 256);
    G_COMP(0, bA);
    G_STORE(1, aB);
    __syncthreads();
    if (t + 2 < 8) { G_LOAD(t + 2, aA, bA, Ap, Bp, 256); }
    G_COMP(1, bB);
    if (t + 2 < 8) { G_STORE(0, aA); }
    __syncthreads();
  }
#pragma unroll
  for (int i = 0; i < 4; ++i)
    Cout[(bm + 4 * ty + i) * 256 + bn + tx] = acc[i];
}

// ---------------------------------------------------------------------------
// K2: A = relu(hA+hB+bc) in-load. Out: PT (bn<128, transposed, +bapp1) or
// PQGW cols 128..767. grid (24,16), 256 threads (proven R12 shape).
__global__ __launch_bounds__(256)
void k2_pqgw(const float* __restrict__ hAB, const float* __restrict__ bc,
             const float* __restrict__ W1, const float* __restrict__ b1,
             const float* __restrict__ Wo2, const float* __restrict__ Wo1,
             float* __restrict__ PQGW, float* __restrict__ PT) {
  __shared__ __align__(16) float Ast[2][32][36];
  const int tid = threadIdx.x;
  const int tx = tid & 31, ty = tid >> 5;
  const int ar = tid >> 3, ac = (tid & 7) * 4;
  const int bm = blockIdx.y * 32, bn = blockIdx.x * 32;
  const int col = bn + tx;
  const float* __restrict__ Bp;
  int ldb;
  if (bn < 128)       { Bp = W1 + col; ldb = 128; }
  else if (bn < 256)  { Bp = W1 + 256 * 128 + (col - 128); ldb = 128; }
  else if (bn < 512)  { Bp = Wo2 + (col - 256); ldb = 256; }
  else                { Bp = Wo1 + (col - 512); ldb = 256; }
  const float* __restrict__ ApA = hAB + (bm + ar) * 256 + ac;
  const float* __restrict__ ApB = ApA + 131072;
  const float* __restrict__ bcp = bc + ac;
  float4 aA, aB;
  float bA[32], bB[32];
  float acc[4] = {0.f, 0.f, 0.f, 0.f};

#define K2_LOAD(T, AREG, BARR)                                         \
  {                                                                    \
    const float4 xa = *reinterpret_cast<const float4*>(ApA + (T) * 32);\
    const float4 xb = *reinterpret_cast<const float4*>(ApB + (T) * 32);\
    const float4 xc = *reinterpret_cast<const float4*>(bcp + (T) * 32);\
    AREG.x = fmaxf(xa.x + xb.x + xc.x, 0.f);                           \
    AREG.y = fmaxf(xa.y + xb.y + xc.y, 0.f);                           \
    AREG.z = fmaxf(xa.z + xb.z + xc.z, 0.f);                           \
    AREG.w = fmaxf(xa.w + xb.w + xc.w, 0.f);                           \
    _Pragma("unroll") for (int kk = 0; kk < 32; ++kk)                  \
        BARR[kk] = Bp[((T) * 32 + kk) * ldb];                          \
  }

  K2_LOAD(0, aA, bA);
  G_STORE(0, aA);
  __syncthreads();
  for (int t = 0; t < 8; t += 2) {
    K2_LOAD(t + 1, aB, bB);
    G_COMP(0, bA);
    G_STORE(1, aB);
    __syncthreads();
    if (t + 2 < 8) { K2_LOAD(t + 2, aA, bA); }
    G_COMP(1, bB);
    if (t + 2 < 8) { G_STORE(0, aA); }
    __syncthreads();
  }
  if (bn < 128) {
    const float bias = b1[col];
#pragma unroll
    for (int i = 0; i < 4; ++i)
      PT[col * 512 + bm + 4 * ty + i] = acc[i] + bias;
  } else {
#pragma unroll
    for (int i = 0; i < 4; ++i)
      PQGW[(bm + 4 * ty + i) * 768 + col] = acc[i];
  }
#undef K2_LOAD
}

// ---------------------------------------------------------------------------
// K34: 256 blocks; block q owns rows r0=2q, r1=2q+1 (same side). Shared
// PT/G streams, shared geo inner dot; E-rows in LDS; out rows + norms.
__global__ __launch_bounds__(256)
void k34_edges_out(const float* __restrict__ PQGW, const float* __restrict__ PT,
                   const float* __restrict__ coords, const float* __restrict__ Wapp2,
                   const float* __restrict__ bapp2, const float* __restrict__ Wg1,
                   const float* __restrict__ bg1, const float* __restrict__ Wg2,
                   const float* __restrict__ bg2, const float* __restrict__ Wa1,
                   const float* __restrict__ ba1, const float* __restrict__ Wa2,
                   const float* __restrict__ ba2, const float* __restrict__ bo,
                   float* __restrict__ outm, float* __restrict__ nrm) {
  __shared__ __align__(16) float4 qqw[128];   // {Q[r0][j], Q[r1][j], W2[j], -}
  __shared__ __align__(16) float sWg1[256], sWg2[32], sGfix0[32], sGfix1[32];
  __shared__ __align__(16) float sE0[256], sE1[256];
  __shared__ float sWa1[16], sBa1[8], sWa2[8], wpart[2][4];
  const int tid = threadIdx.x;
  const int q = blockIdx.x;
  const int r0 = 2 * q, r1 = 2 * q + 1;
  const bool istrack = (r0 < 256);
  const int vbase = istrack ? 256 : 0;

  if (tid < 128) {
    float4 t;
    t.x = PQGW[r0 * 768 + 128 + tid];
    t.y = PQGW[r1 * 768 + 128 + tid];
    t.z = Wapp2[tid];
    t.w = 0.f;
    qqw[tid] = t;
  }
  sWg1[tid] = Wg1[tid];
  if (tid < 32) sWg2[tid] = Wg2[tid];
  if (tid < 16) sWa1[tid] = Wa1[tid];
  if (tid < 8) { sBa1[tid] = ba1[tid]; sWa2[tid] = Wa2[tid]; }
  __syncthreads();
  if (tid < 32) {  // fixed nodes in DST slot: Wg1 rows 4..7
    float g0 = bg1[tid], g1 = g0;
#pragma unroll
    for (int p = 0; p < 4; ++p) {
      g0 = fmaf(coords[r0 * 4 + p], sWg1[(4 + p) * 32 + tid], g0);
      g1 = fmaf(coords[r1 * 4 + p], sWg1[(4 + p) * 32 + tid], g1);
    }
    sGfix0[tid] = g0;
    sGfix1[tid] = g1;
  }
  __syncthreads();

  const int vr = vbase + tid;
  const float* __restrict__ ptb = PT + vr;
  float z0 = 0.f, z1 = 0.f;
#pragma unroll 8
  for (int j = 0; j < 128; ++j) {
    const float4 t = qqw[j];
    const float p = ptb[j * 512];
    float a0 = p + t.x; a0 = a0 > 0.f ? a0 : 0.f; z0 = fmaf(a0, t.z, z0);
    float a1 = p + t.y; a1 = a1 > 0.f ? a1 : 0.f; z1 = fmaf(a1, t.z, z1);
  }
  const float app0 = sigmoidf_(z0 + bapp2[0]);
  const float app1 = sigmoidf_(z1 + bapp2[0]);
  const float4 cp = *reinterpret_cast<const float4*>(coords + vr * 4);
  float gz0 = 0.f, gz1 = 0.f;
#pragma unroll
  for (int m = 0; m < 32; ++m) {
    float dm = cp.x * sWg1[m];
    dm = fmaf(cp.y, sWg1[32 + m], dm);
    dm = fmaf(cp.z, sWg1[64 + m], dm);
    dm = fmaf(cp.w, sWg1[96 + m], dm);
    float h0 = sGfix0[m] + dm;
    h0 = h0 > 0.f ? h0 : 0.f;
    gz0 = fmaf(h0, sWg2[m], gz0);
    float h1 = sGfix1[m] + dm;
    h1 = h1 > 0.f ? h1 : 0.f;
    gz1 = fmaf(h1, sWg2[m], gz1);
  }
  const float geo0 = sigmoidf_(gz0 + bg2[0]);
  const float geo1 = sigmoidf_(gz1 + bg2[0]);
  float ez0 = 0.f, ez1 = 0.f;
#pragma unroll
  for (int m = 0; m < 8; ++m) {
    float h0 = fmaf(app0, sWa1[m], fmaf(geo0, sWa1[8 + m], sBa1[m]));
    h0 = h0 > 0.f ? h0 : 0.f;
    ez0 = fmaf(h0, sWa2[m], ez0);
    float h1 = fmaf(app1, sWa1[m], fmaf(geo1, sWa1[8 + m], sBa1[m]));
    h1 = h1 > 0.f ? h1 : 0.f;
    ez1 = fmaf(h1, sWa2[m], ez1);
  }
  sE0[tid] = sigmoidf_(ez0 + ba2[0]);
  sE1[tid] = sigmoidf_(ez1 + ba2[0]);
  __syncthreads();

  const int c = tid;
  float acc0[4] = {0.f, 0.f, 0.f, 0.f}, acc1[4] = {0.f, 0.f, 0.f, 0.f};
  const float* __restrict__ gcol = PQGW + vbase * 768 + 256 + c;
#pragma unroll 2
  for (int j = 0; j < 256; j += 8) {
    const float4 e0a = *reinterpret_cast<const float4*>(&sE0[j]);
    const float4 e0b = *reinterpret_cast<const float4*>(&sE0[j + 4]);
    const float4 e1a = *reinterpret_cast<const float4*>(&sE1[j]);
    const float4 e1b = *reinterpret_cast<const float4*>(&sE1[j + 4]);
    const float g0 = gcol[(j + 0) * 768];
    const float g1 = gcol[(j + 1) * 768];
    const float g2 = gcol[(j + 2) * 768];
    const float g3 = gcol[(j + 3) * 768];
    const float g4 = gcol[(j + 4) * 768];
    const float g5 = gcol[(j + 5) * 768];
    const float g6 = gcol[(j + 6) * 768];
    const float g7 = gcol[(j + 7) * 768];
    acc0[0] = fmaf(e0a.x, g0, acc0[0]); acc1[0] = fmaf(e1a.x, g0, acc1[0]);
    acc0[1] = fmaf(e0a.y, g1, acc0[1]); acc1[1] = fmaf(e1a.y, g1, acc1[1]);
    acc0[2] = fmaf(e0a.z, g2, acc0[2]); acc1[2] = fmaf(e1a.z, g2, acc1[2]);
    acc0[3] = fmaf(e0a.w, g3, acc0[3]); acc1[3] = fmaf(e1a.w, g3, acc1[3]);
    acc0[0] = fmaf(e0b.x, g4, acc0[0]); acc1[0] = fmaf(e1b.x, g4, acc1[0]);
    acc0[1] = fmaf(e0b.y, g5, acc0[1]); acc1[1] = fmaf(e1b.y, g5, acc1[1]);
    acc0[2] = fmaf(e0b.z, g6, acc0[2]); acc1[2] = fmaf(e1b.z, g6, acc1[2]);
    acc0[3] = fmaf(e0b.w, g7, acc0[3]); acc1[3] = fmaf(e1b.w, g7, acc1[3]);
  }
  const float boc = bo[c];
  float vv0 = PQGW[r0 * 768 + 512 + c] + boc +
              ((acc0[0] + acc0[1]) + (acc0[2] + acc0[3]));
  float vv1 = PQGW[r1 * 768 + 512 + c] + boc +
              ((acc1[0] + acc1[1]) + (acc1[2] + acc1[3]));
  vv0 = vv0 > 0.f ? vv0 : 0.f;
  vv1 = vv1 > 0.f ? vv1 : 0.f;
  outm[r0 * 256 + c] = vv0;
  outm[r1 * 256 + c] = vv1;
  float ns0 = vv0 * vv0, ns1 = vv1 * vv1;
  ns0 = allred16(ns0);
  ns0 += swz_get<0x401F>(ns0);
  ns0 += __shfl_xor(ns0, 32, 64);
  ns1 = allred16(ns1);
  ns1 += swz_get<0x401F>(ns1);
  ns1 += __shfl_xor(ns1, 32, 64);
  if ((tid & 63) == 0) {
    wpart[0][tid >> 6] = ns0;
    wpart[1][tid >> 6] = ns1;
  }
  __syncthreads();
  if (tid == 0)
    nrm[r0] = fmaxf(sqrtf(wpart[0][0] + wpart[0][1] + wpart[0][2] + wpart[0][3]),
                    1e-6f);
  if (tid == 1)
    nrm[r1] = fmaxf(sqrtf(wpart[1][0] + wpart[1][1] + wpart[1][2] + wpart[1][3]),
                    1e-6f);
}

// ---------------------------------------------------------------------------
// K6: Mh = fp16(exp(5*score(cos, iou))) as half2 (bit-identical RNE; k7
// consumes fp16 anyway). grid (8,8).
__global__ __launch_bounds__(256)
void k6_score(const float* __restrict__ outm, const float* __restrict__ nrm,
              const float* __restrict__ co, const float* __restrict__ Wf1,
              const float* __restrict__ bf1, const float* __restrict__ Wf2,
              const float* __restrict__ bf2, h2t* __restrict__ Mh) {
  __shared__ __align__(16) float Ast[2][32][36];
  const int tid = threadIdx.x;
  const int tx = tid & 31, ty = tid >> 5;
  const int ar = tid >> 3, ac = (tid & 7) * 4;
  const int s0 = blockIdx.y * 32, d0 = blockIdx.x * 32;
  const float* __restrict__ Ap = outm + (s0 + ar) * 256 + ac;
  const float* __restrict__ Bp = outm + (256 + d0 + tx) * 256;  // det row, ldb=1
  float4 aA, aB;
  float bA[32], bB[32];
  float acc[4] = {0.f, 0.f, 0.f, 0.f};

  G_LOAD(0, aA, bA, Ap, Bp, 1);
  G_STORE(0, aA);
  __syncthreads();
  for (int t = 0; t < 8; t += 2) {
    G_LOAD(t + 1, aB, bB, Ap, Bp, 1);
    G_COMP(0, bA);
    G_STORE(1, aB);
    __syncthreads();
    if (t + 2 < 8) { G_LOAD(t + 2, aA, bA, Ap, Bp, 1); }
    G_COMP(1, bB);
    if (t + 2 < 8) { G_STORE(0, aA); }
    __syncthreads();
  }
  const float nb = nrm[256 + d0 + tx];
  const float4 B4 = *reinterpret_cast<const float4*>(co + (256 + d0 + tx) * 4);
  const float areaB = (B4.z - B4.x) * (B4.w - B4.y);
  float w1c[8], w1i[8], w2[8];
#pragma unroll
  for (int m = 0; m < 8; ++m) {
    w1c[m] = Wf1[m]; w1i[m] = Wf1[8 + m]; w2[m] = Wf2[m];
  }
  const float bf20 = bf2[0];
#pragma unroll
  for (int i = 0; i < 4; ++i) {
    const int r = s0 + 4 * ty + i;
    const float4 A4 = *reinterpret_cast<const float4*>(co + r * 4);
    const float ix1 = fmaxf(A4.x, B4.x), iy1 = fmaxf(A4.y, B4.y);
    const float ix2 = fminf(A4.z, B4.z), iy2 = fminf(A4.w, B4.w);
    const float inter = fmaxf(ix2 - ix1, 0.f) * fmaxf(iy2 - iy1, 0.f);
    const float areaA = (A4.z - A4.x) * (A4.w - A4.y);
    const float i1 = inter / (areaA + areaB - inter + 1e-8f);
    const float cosv = acc[i] / (nrm[r] * nb);
    float sz = 0.f;
#pragma unroll
    for (int m = 0; m < 8; ++m) {
      float hm = fmaf(cosv, w1c[m], fmaf(i1, w1i[m], bf1[m]));
      hm = hm > 0.f ? hm : 0.f;
      sz = fmaf(hm, w2[m], sz);
    }
    const float score = sigmoidf_(sz + bf20);
    const float mv = expf(5.0f * score);
    const float nbr = __shfl_xor(mv, 1, 64);  // pair (tx even, tx odd)
    if ((tx & 1) == 0)
      Mh[r * 128 + ((d0 + tx) >> 1)] = pack2(mv, nbr);
  }
}

// ---------------------------------------------------------------------------
// K7: Sinkhorn, single 1024-thread block, M register-resident (fp16 from Mh).
__global__ __launch_bounds__(1024)
void k7_sink(const h2t* __restrict__ Mh, float* __restrict__ outp) {
  __shared__ __align__(16) float su_f[256];
  __shared__ __align__(16) float svs_f[256];   // 256*sv
  __shared__ __align__(16) float psum[16][260];
  __shared__ float wsumU[16], wsumV[4];
  const int tid = threadIdx.x, w = tid >> 6, l = tid & 63;
  const float slack = 2.71828182845904523536f;  // exp(LAM*SLACK) = exp(1)
  const float INV256 = 0.00390625f;
  const int rev = ((l & 1) << 3) | ((l & 2) << 1) | ((l & 4) >> 1) | ((l & 8) >> 3);
  const bool b0 = l & 1, b1 = l & 2, b2 = l & 4, b3 = l & 8;

  h2t mrA[16], mrB[16];
#pragma unroll
  for (int i = 0; i < 16; ++i) {
    const uint2 u = *reinterpret_cast<const uint2*>(Mh + (w * 16 + i) * 128 + 2 * l);
    mrA[i] = __builtin_bit_cast(h2t, u.x);
    mrB[i] = __builtin_bit_cast(h2t, u.y);
  }
  if (tid < 256) svs_f[tid] = 256.0f;
  __syncthreads();

  float sv256 = 1.0f;
  for (int it = 0; it < 8; ++it) {
    const float sv_tot =
        (it == 0) ? 257.0f : (wsumV[0] + wsumV[1] + wsumV[2] + wsumV[3] + sv256);
    const float su256 = 1.0f / (slack * sv_tot);
    // row pass
    const float4 va = *reinterpret_cast<const float4*>(&svs_f[4 * l]);
    const h2t sva = pack2(va.x, va.y), svb = pack2(va.z, va.w);
    float p[16];
#pragma unroll
    for (int i = 0; i < 16; ++i) p[i] = fdot2f(mrA[i], sva, fdot2f(mrB[i], svb, 0.0f));
#pragma unroll
    for (int i = 0; i < 8; ++i) {
      const float keep = b0 ? p[i + 8] : p[i], give = b0 ? p[i] : p[i + 8];
      p[i] = keep + dpp_get<0xB1>(give);
    }
#pragma unroll
    for (int i = 0; i < 4; ++i) {
      const float keep = b1 ? p[i + 4] : p[i], give = b1 ? p[i] : p[i + 4];
      p[i] = keep + dpp_get<0x4E>(give);
    }
#pragma unroll
    for (int i = 0; i < 2; ++i) {
      const float keep = b2 ? p[i + 2] : p[i], give = b2 ? p[i] : p[i + 2];
      p[i] = keep + dpp_get<0x141>(give);
    }
    {
      const float keep = b3 ? p[1] : p[0], give = b3 ? p[0] : p[1];
      p[0] = keep + dpp_get<0x140>(give);
    }
    float S = p[0];
    S += swz_get<0x401F>(S);
    S += __shfl_xor(S, 32, 64);
    const float su_val = 1.0f / (S * INV256 + slack * sv256);
    if (l < 16) su_f[w * 16 + rev] = su_val;
    const float wsU = allred16(su_val);
    if (l == 0) wsumU[w] = wsU;
    asm volatile("s_waitcnt lgkmcnt(0)" ::: "memory");  // same-wave su_f readback
    // col partials from row regs
    float su16[16];
#pragma unroll
    for (int k = 0; k < 16; k += 4) {
      const float4 t = *reinterpret_cast<const float4*>(&su_f[w * 16 + k]);
      su16[k] = t.x; su16[k + 1] = t.y; su16[k + 2] = t.z; su16[k + 3] = t.w;
    }
    float pc0 = 0.f, pc1 = 0.f, pc2 = 0.f, pc3 = 0.f;
#pragma unroll
    for (int i = 0; i < 16; ++i) {
      const float ui = su16[i];
      pc0 = fmaf((float)mrA[i].x, ui, pc0);
      pc1 = fmaf((float)mrA[i].y, ui, pc1);
      pc2 = fmaf((float)mrB[i].x, ui, pc2);
      pc3 = fmaf((float)mrB[i].y, ui, pc3);
    }
    float4 pcv; pcv.x = pc0; pcv.y = pc1; pcv.z = pc2; pcv.w = pc3;
    *reinterpret_cast<float4*>(&psum[w][4 * l]) = pcv;
    __syncthreads();
    // sv phase
    const float su_tot = wsumU[0] + wsumU[1] + wsumU[2] + wsumU[3] + wsumU[4] +
                         wsumU[5] + wsumU[6] + wsumU[7] + wsumU[8] + wsumU[9] +
                         wsumU[10] + wsumU[11] + wsumU[12] + wsumU[13] +
                         wsumU[14] + wsumU[15] + su256;
    if (tid < 256) {
      float cs = 0.f;
#pragma unroll
      for (int g = 0; g < 16; ++g) cs += psum[g][tid];
      const float sv_val = 1.0f / (cs + slack * su256);
      svs_f[tid] = 256.0f * sv_val;
      float t = allred16(sv_val);
      t += swz_get<0x401F>(t);
      t += __shfl_xor(t, 32, 64);
      if (l == 0) wsumV[w] = t;
    }
    sv256 = 1.0f / (slack * su_tot);
    __syncthreads();
  }
  const float4 sv4 = *reinterpret_cast<const float4*>(&svs_f[4 * l]);
#pragma unroll
  for (int i = 0; i < 16; ++i) {
    const float uo = su_f[w * 16 + i] * INV256;
    float4 o;
    o.x = uo * (float)mrA[i].x * sv4.x;
    o.y = uo * (float)mrA[i].y * sv4.y;
    o.z = uo * (float)mrB[i].x * sv4.z;
    o.w = uo * (float)mrB[i].y * sv4.w;
    *reinterpret_cast<float4*>(outp + (w * 16 + i) * 256 + 4 * l) = o;
  }
}

// ---------------------------------------------------------------------------
extern "C" void kernel_launch(void* const* d_in, const int* in_sizes, int n_in,
                              void* d_out, int out_size, void* d_ws, size_t ws_size,
                              hipStream_t stream) {
  (void)in_sizes; (void)n_in; (void)out_size; (void)ws_size;
  const float* x      = (const float*)d_in[0];
  const float* coords = (const float*)d_in[1];
  const float* co     = (const float*)d_in[2];
  // d_in[3] = edge_index (int32) — structure is deterministic, not needed
  const float* Wc    = (const float*)d_in[4];
  const float* bc    = (const float*)d_in[5];
  const float* Wapp1 = (const float*)d_in[6];
  const float* bapp1 = (const float*)d_in[7];
  const float* Wapp2 = (const float*)d_in[8];
  const float* bapp2 = (const float*)d_in[9];
  const float* Wg1   = (const float*)d_in[10];
  const float* bg1   = (const float*)d_in[11];
  const float* Wg2   = (const float*)d_in[12];
  const float* bg2   = (const float*)d_in[13];
  const float* Wa1   = (const float*)d_in[14];
  const float* ba1   = (const float*)d_in[15];
  const float* Wa2   = (const float*)d_in[16];
  const float* ba2   = (const float*)d_in[17];
  const float* Wo1   = (const float*)d_in[18];
  const float* Wo2   = (const float*)d_in[19];
  const float* bo    = (const float*)d_in[20];
  const float* Wf1   = (const float*)d_in[21];
  const float* bf1   = (const float*)d_in[22];
  const float* Wf2   = (const float*)d_in[23];
  const float* bf2   = (const float*)d_in[24];

  float* ws   = (float*)d_ws;
  float* hAB  = ws + 0;        // 2 * 512*256
  float* PQGW = ws + 262144;   // 512*768 (cols 0..127 unused)
  float* PT   = ws + 655360;   // 128*512 (P transposed, +bapp1)
  float* outm = ws + 720896;   // 512*256
  float* nrm  = ws + 851968;   // 512
  h2t*   Mh   = (h2t*)(ws + 852480);  // 256*128 half2 (fp16 M)

  k1_h<<<dim3(8, 16, 2), 256, 0, stream>>>(x, Wc, hAB);
  k2_pqgw<<<dim3(24, 16), 256, 0, stream>>>(hAB, bc, Wapp1, bapp1, Wo2, Wo1,
                                            PQGW, PT);
  k34_edges_out<<<256, 256, 0, stream>>>(PQGW, PT, coords, Wapp2, bapp2, Wg1,
                                         bg1, Wg2, bg2, Wa1, ba1, Wa2, ba2, bo,
                                         outm, nrm);
  k6_score<<<dim3(8, 8), 256, 0, stream>>>(outm, nrm, co, Wf1, bf1, Wf2, bf2,
                                           Mh);
  k7_sink<<<1, 1024, 0, stream>>>(Mh, (float*)d_out);
}